// Round 2
// baseline (488.070 us; speedup 1.0000x reference)
//
#include <hip/hip_runtime.h>
#include <math.h>

#define T_SEQ 1152

// ---------------------------------------------------------------------------
// Kernel 0: M[b,s,m] = sum_n spatial_w[n,s] * L_norm[b,n,m]   (B x 4 x 64)
// ---------------------------------------------------------------------------
__global__ void mKernel(const float* __restrict__ L, const float* __restrict__ sw,
                        float* __restrict__ Mbuf) {
  int b = blockIdx.x, tid = threadIdx.x;   // 256 threads
  int s = tid >> 6, m = tid & 63;
  float a = 0.f;
  #pragma unroll 4
  for (int n = 0; n < 64; ++n)
    a = fmaf(sw[n * 4 + s], L[(b * 64 + n) * 64 + m], a);
  Mbuf[b * 256 + s * 64 + m] = a;
}

// ---------------------------------------------------------------------------
// Kernel A: conv(32x1, 8->8, SAME) + LayerNorm(8) + ReLU + projection by M
//   writes snn[b, t, 32]
// Block: (t-tile of 64, b). 256 threads = 8 c x 32 tg x 2 ts.
// 8 c-parts of 8 channels -> LDS 33.6 KB -> 4 blocks/CU (16 waves).
// Projection partials kept in registers (deterministic, no atomics).
// ---------------------------------------------------------------------------
__global__ __launch_bounds__(256, 4)
void convKernel(const float* __restrict__ X, const float* __restrict__ Kw,
                const float* __restrict__ lnS, const float* __restrict__ lnB,
                const float* __restrict__ Mbuf, float* __restrict__ snn) {
  __shared__ float Xs[8 * 8 * 95];    // [i][c][w], w = 0..94 ; aliased by h
  __shared__ float Ks[2048];          // [kh][i][f] (flat input order)
  __shared__ float Ms[256];           // [c][s] for this b  (transposed!)
  __shared__ float lnSs[8], lnBs[8];

  const int tile = blockIdx.x;        // 0..17
  const int b    = blockIdx.y;        // 0..63
  const int tid  = threadIdx.x;       // 0..255
  const int t0   = tile * 64;

  for (int idx = tid; idx < 2048; idx += 256) Ks[idx] = Kw[idx];
  for (int idx = tid; idx < 256;  idx += 256) {
    int s = idx >> 6, m = idx & 63;
    Ms[m * 4 + s] = Mbuf[b * 256 + idx];   // [c][s]
  }
  if (tid < 8) { lnSs[tid] = lnS[tid]; lnBs[tid] = lnB[tid]; }

  const int cL = tid & 7;             // local channel 0..7
  const int tg = tid >> 3;            // 0..31, owns t = tg*2 + ts
  float sacc[8];
  #pragma unroll
  for (int k = 0; k < 8; ++k) sacc[k] = 0.f;

  float* hS = Xs;                     // h aliases Xs (stride 515 per c)

  #pragma unroll 1
  for (int part = 0; part < 8; ++part) {
    __syncthreads();                  // prev-part proj reads done (alias)
    // ---- stage X[b, t0-15 .. t0+79, part*8 + c, i] -> Xs[(i*8+c)*95 + w]
    {
      const float* xb = X + (size_t)(b * T_SEQ) * 512 + part * 64;
      for (int idx = tid; idx < 95 * 16; idx += 256) {
        int w = idx >> 4;             // 0..94
        int q = idx & 15;             // float4 index within 64 floats
        int tg_ = t0 - 15 + w;
        float4 v = make_float4(0.f, 0.f, 0.f, 0.f);
        if (tg_ >= 0 && tg_ < T_SEQ) v = *(const float4*)&xb[(size_t)tg_ * 512 + q * 4];
        int c = q >> 1;               // q*4 = c*8 + i0
        int i0 = (q & 1) * 4;
        Xs[((i0 + 0) * 8 + c) * 95 + w] = v.x;
        Xs[((i0 + 1) * 8 + c) * 95 + w] = v.y;
        Xs[((i0 + 2) * 8 + c) * 95 + w] = v.z;
        Xs[((i0 + 3) * 8 + c) * 95 + w] = v.w;
      }
    }
    __syncthreads();

    // ---- conv: acc[ts][f], output t = t0 + tg*2 + ts
    float acc[2][8];
    #pragma unroll
    for (int ts = 0; ts < 2; ++ts)
      #pragma unroll
      for (int f = 0; f < 8; ++f) acc[ts][f] = 0.f;

    #pragma unroll 1
    for (int i = 0; i < 8; ++i) {
      const float* xrow = &Xs[(i * 8 + cL) * 95 + tg * 2];
      #pragma unroll
      for (int g = 0; g < 4; ++g) {
        float xw[9];
        #pragma unroll
        for (int u = 0; u < 9; ++u) xw[u] = xrow[g * 8 + u];
        #pragma unroll
        for (int u = 0; u < 8; ++u) {
          const int kh = g * 8 + u;
          const float4 k0 = *(const float4*)&Ks[kh * 64 + i * 8];
          const float4 k1 = *(const float4*)&Ks[kh * 64 + i * 8 + 4];
          #pragma unroll
          for (int ts = 0; ts < 2; ++ts) {
            float xv = xw[u + ts];
            acc[ts][0] = fmaf(xv, k0.x, acc[ts][0]);
            acc[ts][1] = fmaf(xv, k0.y, acc[ts][1]);
            acc[ts][2] = fmaf(xv, k0.z, acc[ts][2]);
            acc[ts][3] = fmaf(xv, k0.w, acc[ts][3]);
            acc[ts][4] = fmaf(xv, k1.x, acc[ts][4]);
            acc[ts][5] = fmaf(xv, k1.y, acc[ts][5]);
            acc[ts][6] = fmaf(xv, k1.z, acc[ts][6]);
            acc[ts][7] = fmaf(xv, k1.w, acc[ts][7]);
          }
        }
      }
    }
    __syncthreads();                  // all Xs reads done before h overwrite

    // ---- LayerNorm(8) + ReLU, write h to LDS (stride 515)
    #pragma unroll
    for (int ts = 0; ts < 2; ++ts) {
      float mu = 0.f;
      #pragma unroll
      for (int f = 0; f < 8; ++f) mu += acc[ts][f];
      mu *= 0.125f;
      float var = 0.f;
      #pragma unroll
      for (int f = 0; f < 8; ++f) { float d = acc[ts][f] - mu; var += d * d; }
      var *= 0.125f;
      float r = 1.0f / sqrtf(var + 1e-6f);
      int tloc = tg * 2 + ts;
      #pragma unroll
      for (int f = 0; f < 8; ++f) {
        float h = (acc[ts][f] - mu) * r * lnSs[f] + lnBs[f];
        h = fmaxf(h, 0.f);
        hS[cL * 515 + tloc * 8 + f] = h;
      }
    }
    __syncthreads();

    // ---- projection partial: snn[t, s*8+f] += sum_c M[c,s] * h[c,t,f]
    #pragma unroll
    for (int k = 0; k < 8; ++k) {
      int idx = k * 256 + tid;        // 0..2047 = t*32 + (s*8+f)
      int t = idx >> 5, rr = idx & 31, s = rr >> 3, f = rr & 7;
      float v = 0.f;
      #pragma unroll
      for (int c2 = 0; c2 < 8; ++c2)
        v = fmaf(hS[c2 * 515 + t * 8 + f], Ms[(part * 8 + c2) * 4 + s], v);
      sacc[k] += v;
    }
  }

  // ---- write snn tile
  #pragma unroll
  for (int k = 0; k < 8; ++k) {
    int idx = k * 256 + tid;
    int t = idx >> 5, rr = idx & 31;
    snn[((size_t)(b * T_SEQ) + t0 + t) * 32 + rr] = sacc[k];
  }
}

// ---------------------------------------------------------------------------
// Kernel B: LIF scan. 16 blocks x 64 threads; each thread runs TWO (b,j)
// chains interleaved for ILP on the dependent-FMA chain.
// ---------------------------------------------------------------------------
__global__ void scanKernel(const float* __restrict__ snn, float* __restrict__ flat,
                           float* __restrict__ spkPart) {
  const int tid = threadIdx.x;        // 0..63
  const int j = tid & 31;
  const int g = tid >> 5;             // 0..1
  const int pr = blockIdx.x * 2 + g;  // pair 0..31
  const int b0 = pr * 2, b1 = b0 + 1;
  const float* base0 = snn + (size_t)b0 * T_SEQ * 32 + j;
  const float* base1 = snn + (size_t)b1 * T_SEQ * 32 + j;

  float m10 = 0.f, m20 = 0.f, mo0 = 0.f, s10 = 0.f, s20 = 0.f;
  float m11 = 0.f, m21 = 0.f, mo1 = 0.f, s11 = 0.f, s21 = 0.f;

  for (int ch = 0; ch < 48; ++ch) {
    float parts0[2], parts1[2];
    #pragma unroll
    for (int half = 0; half < 2; ++half) {
      float x0[12], x1[12];
      #pragma unroll
      for (int u = 0; u < 12; ++u) {
        int t = ch * 24 + half * 12 + u;
        x0[u] = base0[(size_t)t * 32];
        x1[u] = base1[(size_t)t * 32];
      }
      float acc0 = 0.f, acc1 = 0.f;
      #pragma unroll
      for (int u = 0; u < 12; ++u) {
        m10 = m10 * 0.8f + x0[u];
        float sp1a = (m10 > 0.5f) ? 1.f : 0.f;  m10 -= sp1a * 0.5f;
        m20 = m20 * 0.9f + sp1a;
        float sp2a = (m20 > 0.5f) ? 1.f : 0.f;  m20 -= sp2a * 0.5f;
        mo0 = mo0 * 0.95f + sp2a;
        s10 += sp1a; s20 += sp2a; acc0 += mo0;

        m11 = m11 * 0.8f + x1[u];
        float sp1b = (m11 > 0.5f) ? 1.f : 0.f;  m11 -= sp1b * 0.5f;
        m21 = m21 * 0.9f + sp1b;
        float sp2b = (m21 > 0.5f) ? 1.f : 0.f;  m21 -= sp2b * 0.5f;
        mo1 = mo1 * 0.95f + sp2b;
        s11 += sp1b; s21 += sp2b; acc1 += mo1;
      }
      parts0[half] = acc0; parts1[half] = acc1;
    }
    flat[b0 * 3072 + ch * 64 + j]      = parts0[0] / 12.0f;
    flat[b0 * 3072 + ch * 64 + 32 + j] = parts0[1] / 12.0f;
    flat[b1 * 3072 + ch * 64 + j]      = parts1[0] / 12.0f;
    flat[b1 * 3072 + ch * 64 + 32 + j] = parts1[1] / 12.0f;
  }
  for (int off = 16; off > 0; off >>= 1) {
    s10 += __shfl_down(s10, off, 32);
    s20 += __shfl_down(s20, off, 32);
    s11 += __shfl_down(s11, off, 32);
    s21 += __shfl_down(s21, off, 32);
  }
  if (j == 0) {
    spkPart[b0 * 2] = s10; spkPart[b0 * 2 + 1] = s20;
    spkPart[b1 * 2] = s11; spkPart[b1 * 2 + 1] = s21;
  }
}

// ---------------------------------------------------------------------------
// Kernel C: y = gelu(flat @ W1 + b1); logits = y @ W2 + b2 ; firing rate.
// ---------------------------------------------------------------------------
__global__ void mlpKernel(const float* __restrict__ flat, const float* __restrict__ W1,
                          const float* __restrict__ b1, const float* __restrict__ W2,
                          const float* __restrict__ b2, const float* __restrict__ spkPart,
                          float* __restrict__ out) {
  if (blockIdx.x == 64) {
    if (threadIdx.x == 0) {
      float s1 = 0.f, s2 = 0.f;
      for (int i = 0; i < 64; ++i) { s1 += spkPart[2 * i]; s2 += spkPart[2 * i + 1]; }
      out[256] = (s1 + s2) * 0.5f / (64.0f * 1152.0f * 32.0f);
    }
    return;
  }
  const int b = blockIdx.x;
  const int tid = threadIdx.x;        // 256
  const int u = tid & 31, kc = tid >> 5;
  __shared__ float red[256];
  __shared__ float ys[32];
  float p = 0.f;
  const int kbeg = kc * 384, kend = kbeg + 384;
  #pragma unroll 4
  for (int k = kbeg; k < kend; ++k)
    p = fmaf(flat[b * 3072 + k], W1[k * 32 + u], p);
  red[tid] = p;
  __syncthreads();
  if (kc == 0) {
    float y = b1[u];
    #pragma unroll
    for (int q = 0; q < 8; ++q) y += red[q * 32 + u];
    float y3 = y * y * y;
    float th = tanhf(0.7978845608028654f * (y + 0.044715f * y3));
    ys[u] = 0.5f * y * (1.0f + th);
  }
  __syncthreads();
  if (tid < 4) {
    float accv = b2[tid];
    #pragma unroll
    for (int q = 0; q < 32; ++q) accv = fmaf(ys[q], W2[q * 4 + tid], accv);
    out[b * 4 + tid] = accv;
  }
}

// ---------------------------------------------------------------------------
extern "C" void kernel_launch(void* const* d_in, const int* in_sizes, int n_in,
                              void* d_out, int out_size, void* d_ws, size_t ws_size,
                              hipStream_t stream) {
  const float* L   = (const float*)d_in[0];
  const float* X   = (const float*)d_in[1];
  // d_in[2] = deterministic (unused)
  const float* Kw  = (const float*)d_in[3];
  const float* lnS = (const float*)d_in[4];
  const float* lnB = (const float*)d_in[5];
  const float* sw  = (const float*)d_in[6];
  const float* W1  = (const float*)d_in[7];
  const float* b1  = (const float*)d_in[8];
  const float* W2  = (const float*)d_in[9];
  const float* b2  = (const float*)d_in[10];

  float* ws   = (float*)d_ws;
  float* Mbuf = ws;                       // 64*4*64      = 16384
  float* snn  = Mbuf + 16384;             // 64*1152*32   = 2359296
  float* flat = snn + 2359296;            // 64*3072      = 196608
  float* spk  = flat + 196608;            // 128
  float* out  = (float*)d_out;

  mKernel<<<64, 256, 0, stream>>>(L, sw, Mbuf);
  convKernel<<<dim3(18, 64), 256, 0, stream>>>(X, Kw, lnS, lnB, Mbuf, snn);
  scanKernel<<<16, 64, 0, stream>>>(snn, flat, spk);
  mlpKernel<<<65, 256, 0, stream>>>(flat, W1, b1, W2, b2, spk, out);
}

// Round 3
// 367.055 us; speedup vs baseline: 1.3297x; 1.3297x over previous
//
#include <hip/hip_runtime.h>
#include <math.h>

#define T_SEQ 1152

// ---------------------------------------------------------------------------
// Kernel 0: M[b,s,m] = sum_n spatial_w[n,s] * L_norm[b,n,m]   (B x 4 x 64)
// ---------------------------------------------------------------------------
__global__ void mKernel(const float* __restrict__ L, const float* __restrict__ sw,
                        float* __restrict__ Mbuf) {
  int b = blockIdx.x, tid = threadIdx.x;   // 256 threads
  int s = tid >> 6, m = tid & 63;
  float a = 0.f;
  #pragma unroll 4
  for (int n = 0; n < 64; ++n)
    a = fmaf(sw[n * 4 + s], L[(b * 64 + n) * 64 + m], a);
  Mbuf[b * 256 + s * 64 + m] = a;
}

// ---------------------------------------------------------------------------
// Kernel A: conv(32x1, 8->8, SAME) + LayerNorm(8) + ReLU + projection by M.
// Key change vs v2: kernel weights K are read straight from GLOBAL memory with
// wave-uniform addresses -> compiler emits s_load (scalar cache, 8KB resident).
// LDS pipe now carries only X reads (b32, <=2-way conflicts).
// Block: 128 threads = 8 c x 16 tg, thread tile = 4t x 1c x 8f.
// 8 c-parts of 8 channels. LDS ~28.5KB -> 5 blocks/CU.
// ---------------------------------------------------------------------------
__global__ __launch_bounds__(128, 2)
void convKernel(const float* __restrict__ X, const float* __restrict__ Kw,
                const float* __restrict__ lnS, const float* __restrict__ lnB,
                const float* __restrict__ Mbuf, float* __restrict__ snn) {
  // Xs layout: [i][w][c] addr = (i*95 + w)*9 + c   (6840 floats)
  // hS layout: [c][t]    addr = c*772 + t*12 + f   (6176 floats, aliases Xs)
  __shared__ float XH[6840];
  __shared__ float Ms[256];            // [c][s]
  __shared__ float lnSs[8], lnBs[8];

  const int tile = blockIdx.x;         // 0..17
  const int b    = blockIdx.y;         // 0..63
  const int tid  = threadIdx.x;        // 0..127
  const int t0   = tile * 64;

  for (int idx = tid; idx < 256; idx += 128) {
    int s = idx >> 6, m = idx & 63;
    Ms[m * 4 + s] = Mbuf[b * 256 + idx];
  }
  if (tid < 8) { lnSs[tid] = lnS[tid]; lnBs[tid] = lnB[tid]; }

  const int cL = tid & 7;              // channel within part
  const int tg = tid >> 3;             // 0..15, owns t = tg*4 + ts
  float sacc[16];
  #pragma unroll
  for (int k = 0; k < 16; ++k) sacc[k] = 0.f;

  #pragma unroll 1
  for (int part = 0; part < 8; ++part) {
    __syncthreads();                   // prev-part proj reads done (alias)
    // ---- stage X[b, t0-15 .. t0+79, part*8+c, i] -> XH[(i*95+w)*9 + c]
    {
      const float* xb = X + (size_t)(b * T_SEQ) * 512 + part * 64;
      for (int idx = tid; idx < 95 * 16; idx += 128) {
        int w = idx >> 4;              // 0..94
        int q = idx & 15;              // float4 index within 64 floats
        int tg_ = t0 - 15 + w;
        float4 v = make_float4(0.f, 0.f, 0.f, 0.f);
        if (tg_ >= 0 && tg_ < T_SEQ) v = *(const float4*)&xb[(size_t)tg_ * 512 + q * 4];
        int c = q >> 1;                // q*4 = c*8 + i0
        int i0 = (q & 1) * 4;
        XH[((i0 + 0) * 95 + w) * 9 + c] = v.x;
        XH[((i0 + 1) * 95 + w) * 9 + c] = v.y;
        XH[((i0 + 2) * 95 + w) * 9 + c] = v.z;
        XH[((i0 + 3) * 95 + w) * 9 + c] = v.w;
      }
    }
    __syncthreads();

    // ---- conv: acc[ts][f], output t = t0 + tg*4 + ts
    float acc[4][8];
    #pragma unroll
    for (int ts = 0; ts < 4; ++ts)
      #pragma unroll
      for (int f = 0; f < 8; ++f) acc[ts][f] = 0.f;

    #pragma unroll 1
    for (int i = 0; i < 8; ++i) {
      const float* xrow = &XH[(i * 95 + tg * 4) * 9 + cL];
      #pragma unroll 1
      for (int g = 0; g < 4; ++g) {
        float xw[11];
        #pragma unroll
        for (int u = 0; u < 11; ++u) xw[u] = xrow[(g * 8 + u) * 9];
        #pragma unroll
        for (int u = 0; u < 8; ++u) {
          const float* kp = Kw + (g * 8 + u) * 64 + i * 8;  // wave-uniform -> s_load
          const float4 k0 = *(const float4*)kp;
          const float4 k1 = *(const float4*)(kp + 4);
          #pragma unroll
          for (int ts = 0; ts < 4; ++ts) {
            float xv = xw[u + ts];
            acc[ts][0] = fmaf(xv, k0.x, acc[ts][0]);
            acc[ts][1] = fmaf(xv, k0.y, acc[ts][1]);
            acc[ts][2] = fmaf(xv, k0.z, acc[ts][2]);
            acc[ts][3] = fmaf(xv, k0.w, acc[ts][3]);
            acc[ts][4] = fmaf(xv, k1.x, acc[ts][4]);
            acc[ts][5] = fmaf(xv, k1.y, acc[ts][5]);
            acc[ts][6] = fmaf(xv, k1.z, acc[ts][6]);
            acc[ts][7] = fmaf(xv, k1.w, acc[ts][7]);
          }
        }
      }
    }
    __syncthreads();                   // Xs reads done before h overwrite

    // ---- LayerNorm(8) + ReLU -> hS[c][t] (b128 writes, 2-way max)
    #pragma unroll
    for (int ts = 0; ts < 4; ++ts) {
      float mu = 0.f;
      #pragma unroll
      for (int f = 0; f < 8; ++f) mu += acc[ts][f];
      mu *= 0.125f;
      float var = 0.f;
      #pragma unroll
      for (int f = 0; f < 8; ++f) { float d = acc[ts][f] - mu; var += d * d; }
      var *= 0.125f;
      float r = 1.0f / sqrtf(var + 1e-6f);
      float hv[8];
      #pragma unroll
      for (int f = 0; f < 8; ++f) {
        float h = (acc[ts][f] - mu) * r * lnSs[f] + lnBs[f];
        hv[f] = fmaxf(h, 0.f);
      }
      int t = tg * 4 + ts;
      *(float4*)&XH[cL * 772 + t * 12]     = make_float4(hv[0], hv[1], hv[2], hv[3]);
      *(float4*)&XH[cL * 772 + t * 12 + 4] = make_float4(hv[4], hv[5], hv[6], hv[7]);
    }
    __syncthreads();

    // ---- projection partial: snn[t, s*8+f] += sum_c M[c,s] * h[c,t,f]
    #pragma unroll
    for (int k = 0; k < 16; ++k) {
      int idx = k * 128 + tid;         // 0..2047 = t*32 + (s*8+f)
      int t = idx >> 5, rr = idx & 31, s = rr >> 3, f = rr & 7;
      float v = 0.f;
      #pragma unroll
      for (int c2 = 0; c2 < 8; ++c2)
        v = fmaf(XH[c2 * 772 + t * 12 + f], Ms[(part * 8 + c2) * 4 + s], v);
      sacc[k] += v;
    }
  }

  // ---- write snn tile
  #pragma unroll
  for (int k = 0; k < 16; ++k) {
    int idx = k * 128 + tid;
    int t = idx >> 5, rr = idx & 31;
    snn[((size_t)(b * T_SEQ) + t0 + t) * 32 + rr] = sacc[k];
  }
}

// ---------------------------------------------------------------------------
// Kernel B: LIF scan. 16 blocks x 64 threads; each thread runs TWO (b,j)
// chains interleaved for ILP on the dependent-FMA chain.
// ---------------------------------------------------------------------------
__global__ void scanKernel(const float* __restrict__ snn, float* __restrict__ flat,
                           float* __restrict__ spkPart) {
  const int tid = threadIdx.x;        // 0..63
  const int j = tid & 31;
  const int g = tid >> 5;             // 0..1
  const int pr = blockIdx.x * 2 + g;  // pair 0..31
  const int b0 = pr * 2, b1 = b0 + 1;
  const float* base0 = snn + (size_t)b0 * T_SEQ * 32 + j;
  const float* base1 = snn + (size_t)b1 * T_SEQ * 32 + j;

  float m10 = 0.f, m20 = 0.f, mo0 = 0.f, s10 = 0.f, s20 = 0.f;
  float m11 = 0.f, m21 = 0.f, mo1 = 0.f, s11 = 0.f, s21 = 0.f;

  for (int ch = 0; ch < 48; ++ch) {
    float parts0[2], parts1[2];
    #pragma unroll
    for (int half = 0; half < 2; ++half) {
      float x0[12], x1[12];
      #pragma unroll
      for (int u = 0; u < 12; ++u) {
        int t = ch * 24 + half * 12 + u;
        x0[u] = base0[(size_t)t * 32];
        x1[u] = base1[(size_t)t * 32];
      }
      float acc0 = 0.f, acc1 = 0.f;
      #pragma unroll
      for (int u = 0; u < 12; ++u) {
        m10 = m10 * 0.8f + x0[u];
        float sp1a = (m10 > 0.5f) ? 1.f : 0.f;  m10 -= sp1a * 0.5f;
        m20 = m20 * 0.9f + sp1a;
        float sp2a = (m20 > 0.5f) ? 1.f : 0.f;  m20 -= sp2a * 0.5f;
        mo0 = mo0 * 0.95f + sp2a;
        s10 += sp1a; s20 += sp2a; acc0 += mo0;

        m11 = m11 * 0.8f + x1[u];
        float sp1b = (m11 > 0.5f) ? 1.f : 0.f;  m11 -= sp1b * 0.5f;
        m21 = m21 * 0.9f + sp1b;
        float sp2b = (m21 > 0.5f) ? 1.f : 0.f;  m21 -= sp2b * 0.5f;
        mo1 = mo1 * 0.95f + sp2b;
        s11 += sp1b; s21 += sp2b; acc1 += mo1;
      }
      parts0[half] = acc0; parts1[half] = acc1;
    }
    flat[b0 * 3072 + ch * 64 + j]      = parts0[0] / 12.0f;
    flat[b0 * 3072 + ch * 64 + 32 + j] = parts0[1] / 12.0f;
    flat[b1 * 3072 + ch * 64 + j]      = parts1[0] / 12.0f;
    flat[b1 * 3072 + ch * 64 + 32 + j] = parts1[1] / 12.0f;
  }
  for (int off = 16; off > 0; off >>= 1) {
    s10 += __shfl_down(s10, off, 32);
    s20 += __shfl_down(s20, off, 32);
    s11 += __shfl_down(s11, off, 32);
    s21 += __shfl_down(s21, off, 32);
  }
  if (j == 0) {
    spkPart[b0 * 2] = s10; spkPart[b0 * 2 + 1] = s20;
    spkPart[b1 * 2] = s11; spkPart[b1 * 2 + 1] = s21;
  }
}

// ---------------------------------------------------------------------------
// Kernel C: y = gelu(flat @ W1 + b1); logits = y @ W2 + b2 ; firing rate.
// ---------------------------------------------------------------------------
__global__ void mlpKernel(const float* __restrict__ flat, const float* __restrict__ W1,
                          const float* __restrict__ b1, const float* __restrict__ W2,
                          const float* __restrict__ b2, const float* __restrict__ spkPart,
                          float* __restrict__ out) {
  if (blockIdx.x == 64) {
    if (threadIdx.x == 0) {
      float s1 = 0.f, s2 = 0.f;
      for (int i = 0; i < 64; ++i) { s1 += spkPart[2 * i]; s2 += spkPart[2 * i + 1]; }
      out[256] = (s1 + s2) * 0.5f / (64.0f * 1152.0f * 32.0f);
    }
    return;
  }
  const int b = blockIdx.x;
  const int tid = threadIdx.x;        // 256
  const int u = tid & 31, kc = tid >> 5;
  __shared__ float red[256];
  __shared__ float ys[32];
  float p = 0.f;
  const int kbeg = kc * 384, kend = kbeg + 384;
  #pragma unroll 4
  for (int k = kbeg; k < kend; ++k)
    p = fmaf(flat[b * 3072 + k], W1[k * 32 + u], p);
  red[tid] = p;
  __syncthreads();
  if (kc == 0) {
    float y = b1[u];
    #pragma unroll
    for (int q = 0; q < 8; ++q) y += red[q * 32 + u];
    float y3 = y * y * y;
    float th = tanhf(0.7978845608028654f * (y + 0.044715f * y3));
    ys[u] = 0.5f * y * (1.0f + th);
  }
  __syncthreads();
  if (tid < 4) {
    float accv = b2[tid];
    #pragma unroll
    for (int q = 0; q < 32; ++q) accv = fmaf(ys[q], W2[q * 4 + tid], accv);
    out[b * 4 + tid] = accv;
  }
}

// ---------------------------------------------------------------------------
extern "C" void kernel_launch(void* const* d_in, const int* in_sizes, int n_in,
                              void* d_out, int out_size, void* d_ws, size_t ws_size,
                              hipStream_t stream) {
  const float* L   = (const float*)d_in[0];
  const float* X   = (const float*)d_in[1];
  // d_in[2] = deterministic (unused)
  const float* Kw  = (const float*)d_in[3];
  const float* lnS = (const float*)d_in[4];
  const float* lnB = (const float*)d_in[5];
  const float* sw  = (const float*)d_in[6];
  const float* W1  = (const float*)d_in[7];
  const float* b1  = (const float*)d_in[8];
  const float* W2  = (const float*)d_in[9];
  const float* b2  = (const float*)d_in[10];

  float* ws   = (float*)d_ws;
  float* Mbuf = ws;                       // 64*4*64      = 16384
  float* snn  = Mbuf + 16384;             // 64*1152*32   = 2359296
  float* flat = snn + 2359296;            // 64*3072      = 196608
  float* spk  = flat + 196608;            // 128
  float* out  = (float*)d_out;

  mKernel<<<64, 256, 0, stream>>>(L, sw, Mbuf);
  convKernel<<<dim3(18, 64), 128, 0, stream>>>(X, Kw, lnS, lnB, Mbuf, snn);
  scanKernel<<<16, 64, 0, stream>>>(snn, flat, spk);
  mlpKernel<<<65, 256, 0, stream>>>(flat, W1, b1, W2, b2, spk, out);
}